// Round 1
// baseline (970.886 us; speedup 1.0000x reference)
//
#include <hip/hip_runtime.h>
#include <hip/hip_bf16.h>

#define N_NODES 100000
#define N_EDGES 1000000
#define C 64

// ---- Stage 2: count in-degree over dst ----
__global__ void count_deg_kernel(const int* __restrict__ dst, unsigned* __restrict__ deg, int E) {
    int e = blockIdx.x * blockDim.x + threadIdx.x;
    if (e < E) {
        atomicAdd(&deg[dst[e]], 1u);
    }
}

// ---- Stage 3: dis[i] = rsqrt(deg[i] + 1)  (+1 = self loop) ----
__global__ void dis_kernel(const unsigned* __restrict__ deg, float* __restrict__ dis, int n) {
    int i = blockIdx.x * blockDim.x + threadIdx.x;
    if (i < n) {
        dis[i] = rsqrtf((float)(deg[i] + 1u));
    }
}

// ---- Stage 4: h = x @ W  (N x 64) @ (64 x 64) ----
// Block = 256 threads, each block computes 64 rows. W cached in LDS.
__global__ void gemm64_kernel(const float* __restrict__ x, const float* __restrict__ W,
                              float* __restrict__ h, int n) {
    __shared__ float Wl[64 * 64];
    int tid = threadIdx.x;
    // load W (4096 floats) via float4: 1024 float4, 256 threads -> 4 each
    for (int i = tid; i < 1024; i += 256) {
        ((float4*)Wl)[i] = ((const float4*)W)[i];
    }
    __syncthreads();
    int c  = tid & 63;
    int rq = tid >> 6;              // 0..3
    int base = blockIdx.x * 64;
    for (int j = 0; j < 16; ++j) {
        int row = base + rq * 16 + j;
        if (row < n) {
            const float* xr = x + row * C;
            float sum = 0.0f;
            #pragma unroll
            for (int k = 0; k < C; ++k) {
                sum += xr[k] * Wl[k * 64 + c];
            }
            h[row * C + c] = sum;
        }
    }
}

// ---- Stage 5: out[i][c] = dis[i]^2 * h[i][c] + b[c]  (self-loop term + bias, init) ----
__global__ void init_out_kernel(const float* __restrict__ h, const float* __restrict__ dis,
                                const float* __restrict__ b, float* __restrict__ out, int n) {
    int tid = blockIdx.x * blockDim.x + threadIdx.x;
    int row = tid >> 6;
    int c   = tid & 63;
    if (row < n) {
        float di = dis[row];
        out[tid] = di * di * h[tid] + b[c];
    }
}

// ---- Stage 6: scatter edges: out[dst] += dis[src]*dis[dst] * h[src] ----
// 16 threads per edge; each thread handles 4 consecutive channels (float4 read, 4 atomics).
__global__ void scatter_kernel(const int* __restrict__ src, const int* __restrict__ dst,
                               const float* __restrict__ dis, const float* __restrict__ h,
                               float* __restrict__ out, int E) {
    int tid  = blockIdx.x * blockDim.x + threadIdx.x;
    int e    = tid >> 4;
    int lane = tid & 15;
    if (e >= E) return;
    int s = src[e];
    int d = dst[e];
    float nrm = dis[s] * dis[d];
    float4 hv = ((const float4*)(h + (long long)s * C))[lane];
    float* op = out + (long long)d * C + lane * 4;
    atomicAdd(op + 0, nrm * hv.x);
    atomicAdd(op + 1, nrm * hv.y);
    atomicAdd(op + 2, nrm * hv.z);
    atomicAdd(op + 3, nrm * hv.w);
}

extern "C" void kernel_launch(void* const* d_in, const int* in_sizes, int n_in,
                              void* d_out, int out_size, void* d_ws, size_t ws_size,
                              hipStream_t stream) {
    const float* x   = (const float*)d_in[0];
    const int*   ei  = (const int*)d_in[1];   // [2, E] row-major: src = ei[e], dst = ei[E+e]
    const float* W   = (const float*)d_in[2];
    const float* b   = (const float*)d_in[3];
    float*       out = (float*)d_out;

    const int N = in_sizes[0] / C;       // 100000
    const int E = in_sizes[1] / 2;       // 1000000
    const int* src = ei;
    const int* dst = ei + E;

    // workspace layout
    char* ws = (char*)d_ws;
    unsigned* deg = (unsigned*)ws;                    // N u32
    float*    dis = (float*)(ws + ((size_t)N * 4 + 255) / 256 * 256);
    float*    h   = (float*)((char*)dis + ((size_t)N * 4 + 255) / 256 * 256);

    // 1. zero degree counters
    hipMemsetAsync(deg, 0, (size_t)N * sizeof(unsigned), stream);

    // 2. degree count
    {
        int threads = 256, blocks = (E + threads - 1) / threads;
        count_deg_kernel<<<blocks, threads, 0, stream>>>(dst, deg, E);
    }
    // 3. deg^{-1/2}
    {
        int threads = 256, blocks = (N + threads - 1) / threads;
        dis_kernel<<<blocks, threads, 0, stream>>>(deg, dis, N);
    }
    // 4. h = x @ W
    {
        int threads = 256, blocks = (N + 63) / 64;
        gemm64_kernel<<<blocks, threads, 0, stream>>>(x, W, h, N);
    }
    // 5. out init with self-loop + bias
    {
        long long total = (long long)N * C;
        int threads = 256;
        long long blocks = (total + threads - 1) / threads;
        init_out_kernel<<<(int)blocks, threads, 0, stream>>>(h, dis, b, out, N);
    }
    // 6. edge scatter
    {
        long long total = (long long)E * 16;
        int threads = 256;
        long long blocks = (total + threads - 1) / threads;
        scatter_kernel<<<(int)blocks, threads, 0, stream>>>(src, dst, dis, h, out, E);
    }
}

// Round 2
// 288.779 us; speedup vs baseline: 3.3620x; 3.3620x over previous
//
#include <hip/hip_runtime.h>
#include <hip/hip_bf16.h>

#define C 64

// ---- count in-degree over dst ----
__global__ void count_deg_kernel(const int* __restrict__ dst, unsigned* __restrict__ deg, int E) {
    int e = blockIdx.x * blockDim.x + threadIdx.x;
    if (e < E) {
        atomicAdd(&deg[dst[e]], 1u);
    }
}

// ---- dis[i] = rsqrt(deg[i] + 1)  (+1 = self loop) ----
__global__ void dis_kernel(const unsigned* __restrict__ deg, float* __restrict__ dis, int n) {
    int i = blockIdx.x * blockDim.x + threadIdx.x;
    if (i < n) {
        dis[i] = rsqrtf((float)(deg[i] + 1u));
    }
}

// ---- exclusive scan, level 1: 1024 elems per block (256 thr x 4) ----
__global__ void scan1_kernel(const unsigned* __restrict__ deg, unsigned* __restrict__ offs,
                             unsigned* __restrict__ bsum, int n) {
    __shared__ unsigned s[256];
    int t = threadIdx.x;
    int base = blockIdx.x * 1024 + t * 4;
    unsigned v0 = 0, v1 = 0, v2 = 0, v3 = 0;
    if (base + 0 < n) v0 = deg[base + 0];
    if (base + 1 < n) v1 = deg[base + 1];
    if (base + 2 < n) v2 = deg[base + 2];
    if (base + 3 < n) v3 = deg[base + 3];
    s[t] = v0 + v1 + v2 + v3;
    __syncthreads();
    for (int d = 1; d < 256; d <<= 1) {
        unsigned val = (t >= d) ? s[t - d] : 0u;
        __syncthreads();
        s[t] += val;
        __syncthreads();
    }
    unsigned excl = (t == 0) ? 0u : s[t - 1];
    if (t == 255) bsum[blockIdx.x] = s[255];
    if (base + 0 < n) offs[base + 0] = excl;
    if (base + 1 < n) offs[base + 1] = excl + v0;
    if (base + 2 < n) offs[base + 2] = excl + v0 + v1;
    if (base + 3 < n) offs[base + 3] = excl + v0 + v1 + v2;
}

// ---- scan block sums (single block; nb <= 256) ----
__global__ void scan2_kernel(unsigned* __restrict__ bsum, int nb) {
    __shared__ unsigned s[256];
    int t = threadIdx.x;
    s[t] = (t < nb) ? bsum[t] : 0u;
    __syncthreads();
    for (int d = 1; d < 256; d <<= 1) {
        unsigned val = (t >= d) ? s[t - d] : 0u;
        __syncthreads();
        s[t] += val;
        __syncthreads();
    }
    if (t < nb) bsum[t] = (t == 0) ? 0u : s[t - 1];
}

// ---- add scanned block sums back ----
__global__ void scan3_kernel(unsigned* __restrict__ offs, const unsigned* __restrict__ bsum, int n) {
    int i = blockIdx.x * blockDim.x + threadIdx.x;
    if (i < n) offs[i] += bsum[i >> 10];
}

// ---- bucket edges by dst (counting sort placement) ----
__global__ void bucket_kernel(const int* __restrict__ src, const int* __restrict__ dst,
                              const unsigned* __restrict__ offs, unsigned* __restrict__ cursor,
                              unsigned* __restrict__ ssrc, int E) {
    int e = blockIdx.x * blockDim.x + threadIdx.x;
    if (e < E) {
        int d = dst[e];
        unsigned pos = offs[d] + atomicAdd(&cursor[d], 1u);
        ssrc[pos] = (unsigned)src[e];
    }
}

// ---- h = x @ W  (N x 64) @ (64 x 64), W in LDS ----
__global__ void gemm64_kernel(const float* __restrict__ x, const float* __restrict__ W,
                              float* __restrict__ h, int n) {
    __shared__ float Wl[64 * 64];
    int tid = threadIdx.x;
    for (int i = tid; i < 1024; i += 256) {
        ((float4*)Wl)[i] = ((const float4*)W)[i];
    }
    __syncthreads();
    int c  = tid & 63;
    int rq = tid >> 6;
    int base = blockIdx.x * 64;
    for (int j = 0; j < 16; ++j) {
        int row = base + rq * 16 + j;
        if (row < n) {
            const float* xr = x + row * C;
            float sum = 0.0f;
            #pragma unroll
            for (int k = 0; k < C; ++k) {
                sum += xr[k] * Wl[k * 64 + c];
            }
            h[row * C + c] = sum;
        }
    }
}

// ---- gather: one wave per node; lane = channel ----
__global__ void gather_kernel(const unsigned* __restrict__ offs, const unsigned* __restrict__ deg,
                              const unsigned* __restrict__ ssrc, const float* __restrict__ dis,
                              const float* __restrict__ h, const float* __restrict__ b,
                              float* __restrict__ out, int n) {
    int node = blockIdx.x * 4 + (threadIdx.x >> 6);
    int c    = threadIdx.x & 63;
    if (node >= n) return;
    unsigned off = offs[node];
    unsigned dg  = deg[node];
    float di = dis[node];
    float acc = 0.0f;                    // sum over edges of dis[s]*h[s][c]
    for (unsigned k = 0; k < dg; ++k) {
        unsigned s = ssrc[off + k];
        acc += dis[s] * h[(size_t)s * C + c];
    }
    out[(size_t)node * C + c] = di * di * h[(size_t)node * C + c] + di * acc + b[c];
}

extern "C" void kernel_launch(void* const* d_in, const int* in_sizes, int n_in,
                              void* d_out, int out_size, void* d_ws, size_t ws_size,
                              hipStream_t stream) {
    const float* x   = (const float*)d_in[0];
    const int*   ei  = (const int*)d_in[1];   // [2, E]: src = ei[e], dst = ei[E+e]
    const float* W   = (const float*)d_in[2];
    const float* b   = (const float*)d_in[3];
    float*       out = (float*)d_out;

    const int N = in_sizes[0] / C;
    const int E = in_sizes[1] / 2;
    const int* src = ei;
    const int* dst = ei + E;

    // workspace layout (256B aligned slots)
    char* ws = (char*)d_ws;
    size_t o = 0;
    auto carve = [&](size_t bytes) { char* p = ws + o; o = (o + bytes + 255) & ~(size_t)255; return p; };
    unsigned* deg    = (unsigned*)carve((size_t)N * 4);
    unsigned* offs   = (unsigned*)carve((size_t)N * 4);
    unsigned* bsum   = (unsigned*)carve(1024 * 4);
    unsigned* cursor = (unsigned*)carve((size_t)N * 4);
    float*    dis    = (float*)carve((size_t)N * 4);
    unsigned* ssrc   = (unsigned*)carve((size_t)E * 4);
    float*    h      = (float*)carve((size_t)N * C * 4);

    // zero counters
    hipMemsetAsync(deg, 0, (size_t)N * 4, stream);
    hipMemsetAsync(cursor, 0, (size_t)N * 4, stream);

    // degree histogram
    count_deg_kernel<<<(E + 255) / 256, 256, 0, stream>>>(dst, deg, E);
    // dis = rsqrt(deg+1)
    dis_kernel<<<(N + 255) / 256, 256, 0, stream>>>(deg, dis, N);

    // exclusive prefix sum of deg -> offs
    int nb = (N + 1023) / 1024;
    scan1_kernel<<<nb, 256, 0, stream>>>(deg, offs, bsum, N);
    scan2_kernel<<<1, 256, 0, stream>>>(bsum, nb);
    scan3_kernel<<<(N + 255) / 256, 256, 0, stream>>>(offs, bsum, N);

    // counting-sort edges by dst
    bucket_kernel<<<(E + 255) / 256, 256, 0, stream>>>(src, dst, offs, cursor, ssrc, E);

    // h = x @ W
    gemm64_kernel<<<(N + 63) / 64, 256, 0, stream>>>(x, W, h, N);

    // gather + self loop + bias
    gather_kernel<<<(N + 3) / 4, 256, 0, stream>>>(offs, deg, ssrc, dis, h, b, out, N);
}

// Round 3
// 221.612 us; speedup vs baseline: 4.3810x; 1.3031x over previous
//
#include <hip/hip_runtime.h>
#include <hip/hip_bf16.h>

#define C 64

// ---- count in-degree over dst ----
__global__ void count_deg_kernel(const int* __restrict__ dst, unsigned* __restrict__ deg, int E) {
    int e = blockIdx.x * blockDim.x + threadIdx.x;
    if (e < E) {
        atomicAdd(&deg[dst[e]], 1u);
    }
}

// ---- exclusive scan level 1 (1024/block) + dis = rsqrt(deg+1) fused ----
__global__ void scan1_kernel(const unsigned* __restrict__ deg, unsigned* __restrict__ offs,
                             unsigned* __restrict__ bsum, float* __restrict__ dis, int n) {
    __shared__ unsigned s[256];
    int t = threadIdx.x;
    int base = blockIdx.x * 1024 + t * 4;
    unsigned v0 = 0, v1 = 0, v2 = 0, v3 = 0;
    if (base + 0 < n) v0 = deg[base + 0];
    if (base + 1 < n) v1 = deg[base + 1];
    if (base + 2 < n) v2 = deg[base + 2];
    if (base + 3 < n) v3 = deg[base + 3];
    // fused dis
    if (base + 0 < n) dis[base + 0] = rsqrtf((float)(v0 + 1u));
    if (base + 1 < n) dis[base + 1] = rsqrtf((float)(v1 + 1u));
    if (base + 2 < n) dis[base + 2] = rsqrtf((float)(v2 + 1u));
    if (base + 3 < n) dis[base + 3] = rsqrtf((float)(v3 + 1u));
    s[t] = v0 + v1 + v2 + v3;
    __syncthreads();
    for (int d = 1; d < 256; d <<= 1) {
        unsigned val = (t >= d) ? s[t - d] : 0u;
        __syncthreads();
        s[t] += val;
        __syncthreads();
    }
    unsigned excl = (t == 0) ? 0u : s[t - 1];
    if (t == 255) bsum[blockIdx.x] = s[255];
    if (base + 0 < n) offs[base + 0] = excl;
    if (base + 1 < n) offs[base + 1] = excl + v0;
    if (base + 2 < n) offs[base + 2] = excl + v0 + v1;
    if (base + 3 < n) offs[base + 3] = excl + v0 + v1 + v2;
}

// ---- scan block sums (single block; nb <= 256) ----
__global__ void scan2_kernel(unsigned* __restrict__ bsum, int nb) {
    __shared__ unsigned s[256];
    int t = threadIdx.x;
    s[t] = (t < nb) ? bsum[t] : 0u;
    __syncthreads();
    for (int d = 1; d < 256; d <<= 1) {
        unsigned val = (t >= d) ? s[t - d] : 0u;
        __syncthreads();
        s[t] += val;
        __syncthreads();
    }
    if (t < nb) bsum[t] = (t == 0) ? 0u : s[t - 1];
}

// ---- bucket edges by dst; offs fixed up with bsum on the fly ----
__global__ void bucket_kernel(const int* __restrict__ src, const int* __restrict__ dst,
                              const unsigned* __restrict__ offs, const unsigned* __restrict__ bsum,
                              unsigned* __restrict__ cursor, unsigned* __restrict__ ssrc, int E) {
    int e = blockIdx.x * blockDim.x + threadIdx.x;
    if (e < E) {
        int d = dst[e];
        unsigned pos = offs[d] + bsum[d >> 10] + atomicAdd(&cursor[d], 1u);
        ssrc[pos] = (unsigned)src[e];
    }
}

// ---- hs = dis[row] * (x @ W)  (N x 64), W in LDS ----
__global__ void gemm64_kernel(const float* __restrict__ x, const float* __restrict__ W,
                              const float* __restrict__ dis, float* __restrict__ hs, int n) {
    __shared__ float Wl[64 * 64];
    int tid = threadIdx.x;
    for (int i = tid; i < 1024; i += 256) {
        ((float4*)Wl)[i] = ((const float4*)W)[i];
    }
    __syncthreads();
    int c  = tid & 63;
    int rq = tid >> 6;
    int base = blockIdx.x * 64;
    for (int j = 0; j < 16; ++j) {
        int row = base + rq * 16 + j;
        if (row < n) {
            const float* xr = x + (size_t)row * C;
            float sum = 0.0f;
            #pragma unroll
            for (int k = 0; k < C; ++k) {
                sum += xr[k] * Wl[k * 64 + c];
            }
            hs[(size_t)row * C + c] = sum * dis[row];
        }
    }
}

// ---- gather: one wave per node; 4 edges in flight (16 lanes x float4 each) ----
__global__ void gather_kernel(const unsigned* __restrict__ offs, const unsigned* __restrict__ bsum,
                              const unsigned* __restrict__ deg, const unsigned* __restrict__ ssrc,
                              const float* __restrict__ dis, const float* __restrict__ hs,
                              const float* __restrict__ b, float* __restrict__ out, int n) {
    int node = blockIdx.x * 4 + (threadIdx.x >> 6);
    if (node >= n) return;
    int lane = threadIdx.x & 63;
    int g = lane >> 4;          // edge group 0..3
    int l = lane & 15;          // float4 slot within row
    unsigned off = offs[node] + bsum[node >> 10];
    unsigned dg  = deg[node];
    float4 acc = {0.f, 0.f, 0.f, 0.f};
    unsigned k = 0;
    // 8 edges in flight
    for (; k + 8 <= dg; k += 8) {
        unsigned s0 = ssrc[off + k + g];
        unsigned s1 = ssrc[off + k + 4 + g];
        float4 v0 = ((const float4*)(hs + (size_t)s0 * C))[l];
        float4 v1 = ((const float4*)(hs + (size_t)s1 * C))[l];
        acc.x += v0.x + v1.x; acc.y += v0.y + v1.y;
        acc.z += v0.z + v1.z; acc.w += v0.w + v1.w;
    }
    // 4 edges
    if (k + 4 <= dg) {
        unsigned s0 = ssrc[off + k + g];
        float4 v0 = ((const float4*)(hs + (size_t)s0 * C))[l];
        acc.x += v0.x; acc.y += v0.y; acc.z += v0.z; acc.w += v0.w;
        k += 4;
    }
    // tail (<4)
    if (k + g < dg) {
        unsigned s0 = ssrc[off + k + g];
        float4 v0 = ((const float4*)(hs + (size_t)s0 * C))[l];
        acc.x += v0.x; acc.y += v0.y; acc.z += v0.z; acc.w += v0.w;
    }
    // reduce across the 4 edge groups (lanes l, l+16, l+32, l+48)
    acc.x += __shfl_xor(acc.x, 16); acc.y += __shfl_xor(acc.y, 16);
    acc.z += __shfl_xor(acc.z, 16); acc.w += __shfl_xor(acc.w, 16);
    acc.x += __shfl_xor(acc.x, 32); acc.y += __shfl_xor(acc.y, 32);
    acc.z += __shfl_xor(acc.z, 32); acc.w += __shfl_xor(acc.w, 32);
    if (g == 0) {
        float di = dis[node];
        float4 hv = ((const float4*)(hs + (size_t)node * C))[l];
        float4 bv = ((const float4*)b)[l];
        float4 o;
        o.x = di * (hv.x + acc.x) + bv.x;
        o.y = di * (hv.y + acc.y) + bv.y;
        o.z = di * (hv.z + acc.z) + bv.z;
        o.w = di * (hv.w + acc.w) + bv.w;
        ((float4*)(out + (size_t)node * C))[l] = o;
    }
}

extern "C" void kernel_launch(void* const* d_in, const int* in_sizes, int n_in,
                              void* d_out, int out_size, void* d_ws, size_t ws_size,
                              hipStream_t stream) {
    const float* x   = (const float*)d_in[0];
    const int*   ei  = (const int*)d_in[1];   // [2, E]: src = ei[e], dst = ei[E+e]
    const float* W   = (const float*)d_in[2];
    const float* b   = (const float*)d_in[3];
    float*       out = (float*)d_out;

    const int N = in_sizes[0] / C;
    const int E = in_sizes[1] / 2;
    const int* src = ei;
    const int* dst = ei + E;

    // workspace layout (256B aligned slots); deg+cursor adjacent for one memset
    char* ws = (char*)d_ws;
    size_t o = 0;
    auto carve = [&](size_t bytes) { char* p = ws + o; o = (o + bytes + 255) & ~(size_t)255; return p; };
    unsigned* deg    = (unsigned*)carve((size_t)N * 4);
    unsigned* cursor = (unsigned*)carve((size_t)N * 4);
    unsigned* offs   = (unsigned*)carve((size_t)N * 4);
    unsigned* bsum   = (unsigned*)carve(1024 * 4);
    float*    dis    = (float*)carve((size_t)N * 4);
    unsigned* ssrc   = (unsigned*)carve((size_t)E * 4);
    float*    hs     = (float*)carve((size_t)N * C * 4);

    // zero deg + cursor in one shot (adjacent carves)
    hipMemsetAsync(deg, 0, (size_t)((char*)offs - (char*)deg), stream);

    // degree histogram
    count_deg_kernel<<<(E + 255) / 256, 256, 0, stream>>>(dst, deg, E);

    // exclusive prefix sum of deg -> offs (+ fused dis)
    int nb = (N + 1023) / 1024;
    scan1_kernel<<<nb, 256, 0, stream>>>(deg, offs, bsum, dis, N);
    scan2_kernel<<<1, 256, 0, stream>>>(bsum, nb);

    // counting-sort edges by dst (bsum folded in)
    bucket_kernel<<<(E + 255) / 256, 256, 0, stream>>>(src, dst, offs, bsum, cursor, ssrc, E);

    // hs = dis * (x @ W)
    gemm64_kernel<<<(N + 63) / 64, 256, 0, stream>>>(x, W, dis, hs, N);

    // gather + self loop + bias
    gather_kernel<<<(N + 3) / 4, 256, 0, stream>>>(offs, bsum, deg, ssrc, dis, hs, b, out, N);
}